// Round 10
// baseline (152.599 us; speedup 1.0000x reference)
//
#include <hip/hip_runtime.h>
#include <hip/hip_bf16.h>

// Problem constants (fixed by reference setup_inputs)
constexpr int NWIN = 49;     // 7x7 windows
constexpr int QLD  = 52;     // padded row length for 49-length rows (13 float4)

// workspace layout (float offsets). ws + bars are contiguous -> ONE memset.
constexpr int OFF_WS   = 0;            // [8][64][52]      = 26624 (bt, s, win)
constexpr int OFF_BARF = 26624;        // 640 ints (barrier counters)
constexpr int OFF_Q    = 27264;        // [2][128][4][52]  = 53248 (b, d, t, n)
constexpr int OFF_QSP  = 80512;        // [2][4][128][64]  = 65536 (b, t, d, s)
constexpr int OFF_A12  = 146048;       // [2][3][64][64]
constexpr int OFF_A12T = 170624;
constexpr int OFF_A21  = 195200;
constexpr int OFF_A21T = 219776;       // end = 244352 floats (~977 KB)

// barrier counters: 8 group counters 128 B apart + root at [256]
constexpr int B0 = 0;        // stage 0 (front done):  256 arrivals
constexpr int B1 = 288;      // stage 1 (qsp done):    256 arrivals
constexpr int C2 = 576;      // stage 2 (As done):     6 arrivals

// ---------------------------------------------------------------------------
// Fences: one explicit agent fence per transition; RELAXED atomics carry no
// per-iteration cache maintenance (the R7->R8 lesson).
__device__ __forceinline__ void fence_rel() {
    __builtin_amdgcn_fence(__ATOMIC_RELEASE, "agent");   // L2 writeback
}
__device__ __forceinline__ void fence_acq() {
    __builtin_amdgcn_fence(__ATOMIC_ACQUIRE, "agent");   // L2/L1 invalidate
}
// arrival: 1 relaxed RMW on one of 8 spread lines; 32nd of group bumps root.
__device__ __forceinline__ void arrive8(int* base) {
    int g = (int)(blockIdx.x & 7);
    int prev = __hip_atomic_fetch_add(&base[g * 32], 1, __ATOMIC_RELAXED,
                                      __HIP_MEMORY_SCOPE_AGENT);
    if (prev == 31)
        __hip_atomic_fetch_add(&base[256], 1, __ATOMIC_RELAXED,
                               __HIP_MEMORY_SCOPE_AGENT);
}
__device__ __forceinline__ void poll8(int* base) {
    while (__hip_atomic_load(&base[256], __ATOMIC_RELAXED,
                             __HIP_MEMORY_SCOPE_AGENT) < 8)
        __builtin_amdgcn_s_sleep(4);
}

// ---------------------------------------------------------------------------
// Chain helpers (proven): XOR-4-swizzled LDS, register prefetch.
// Layout: element (r,k) at M[r*64 + (((k>>2)^(r&15))<<2)+(k&3)].
__device__ __forceinline__ void dump_mat(float* M, const float4* v) {
    #pragma unroll
    for (int it = 0; it < 4; ++it) {
        int idx = it * 256 + (int)threadIdx.x;
        int r = idx >> 4, c4 = (idx & 15) << 2;
        *(float4*)&M[r * 64 + (c4 ^ ((r & 15) << 2))] = v[it];
    }
}

__device__ __forceinline__ void mmh_sw(float* acc, const float* Ra, const float* Rb) {
    int lt = threadIdx.x & 127;
    int nl = lt >> 3, ml = lt & 7;
    int sxa = nl << 2;
    #pragma unroll
    for (int k0 = 0; k0 < 64; k0 += 4) {
        float4 av[4], bv[8];
        #pragma unroll
        for (int i = 0; i < 4; ++i)
            av[i] = *(const float4*)&Ra[(nl + 16 * i) * 64 + (k0 ^ sxa)];
        #pragma unroll
        for (int j = 0; j < 8; ++j) {
            int m = ml + 8 * j;
            bv[j] = *(const float4*)&Rb[m * 64 + (k0 ^ ((m & 15) << 2))];
        }
        #pragma unroll
        for (int i = 0; i < 4; ++i)
            #pragma unroll
            for (int j = 0; j < 8; ++j)
                acc[i * 8 + j] += av[i].x * bv[j].x + av[i].y * bv[j].y
                                + av[i].z * bv[j].z + av[i].w * bv[j].w;
    }
}

__device__ __forceinline__ void wrh_sw(float* M, const float* acc) {
    int lt = threadIdx.x & 127;
    int nl = lt >> 3, ml = lt & 7;
    #pragma unroll
    for (int i = 0; i < 4; ++i)
        #pragma unroll
        for (int j = 0; j < 8; ++j) {
            int r = nl + 16 * i, k = ml + 8 * j;
            M[r * 64 + (((k & ~3) ^ ((r & 15) << 2)) | (k & 3))] = acc[i * 8 + j];
        }
}

__device__ __forceinline__ void mm256_sw(float* acc, const float* Ra, const float* Rb) {
    int tid = threadIdx.x;
    int nl = tid >> 4, ml = tid & 15;
    int sxa = nl << 2, sxb = ml << 2;
    #pragma unroll
    for (int i = 0; i < 16; ++i) acc[i] = 0.f;
    #pragma unroll 4
    for (int k0 = 0; k0 < 64; k0 += 4) {
        float4 av[4], bv[4];
        #pragma unroll
        for (int i = 0; i < 4; ++i)
            av[i] = *(const float4*)&Ra[(nl + 16 * i) * 64 + (k0 ^ sxa)];
        #pragma unroll
        for (int j = 0; j < 4; ++j)
            bv[j] = *(const float4*)&Rb[(ml + 16 * j) * 64 + (k0 ^ sxb)];
        #pragma unroll
        for (int i = 0; i < 4; ++i)
            #pragma unroll
            for (int j = 0; j < 4; ++j)
                acc[i * 4 + j] += av[i].x * bv[j].x + av[i].y * bv[j].y
                                + av[i].z * bv[j].z + av[i].w * bv[j].w;
    }
}

__device__ __forceinline__ void store_loss(const float* acc, float* __restrict__ aa,
                                           float* __restrict__ out, float* red) {
    int tid = threadIdx.x;
    int nl = tid >> 4, ml = tid & 15;
    #pragma unroll
    for (int i = 0; i < 4; ++i)
        #pragma unroll
        for (int j = 0; j < 4; ++j)
            aa[(nl + 16 * i) * 64 + (ml + 16 * j)] = acc[i * 4 + j];
    int l = tid & 63;
    float part = 0.f;
    #pragma unroll
    for (int i = 0; i < 4; ++i) {
        float rsum = acc[i * 4 + 0] + acc[i * 4 + 1] + acc[i * 4 + 2] + acc[i * 4 + 3];
        rsum += __shfl_down(rsum, 8, 16);
        rsum += __shfl_down(rsum, 4, 16);
        rsum += __shfl_down(rsum, 2, 16);
        rsum += __shfl_down(rsum, 1, 16);
        float dv = __shfl(acc[5 * i], (l & 48) | nl, 64);
        if ((l & 15) == 0) part += logf(rsum + 6.4e-19f) - logf(dv + 1e-20f);
    }
    for (int off = 32; off; off >>= 1) part += __shfl_down(part, off);
    if (l == 0) red[tid >> 6] = part;
    __syncthreads();
    if (tid == 0) atomicAdd(out, (red[0] + red[1] + red[2] + red[3]) * (1.f / 128.f));
}

// ---------------------------------------------------------------------------
// THE kernel: all phases fused, grid = 256 blocks x 256 threads (1 block/CU).
__global__ void __launch_bounds__(256, 2)
k_all(const int* __restrict__ mask, const float* __restrict__ feats,
      const float* __restrict__ Wh, float* __restrict__ ws,
      float* __restrict__ q, float* __restrict__ qsp,
      float* __restrict__ a12, float* __restrict__ a12T,
      float* __restrict__ a21, float* __restrict__ a21T,
      float* __restrict__ out, int* __restrict__ bars) {
    __shared__ __align__(16) float SMEM[16384];     // 64 KB, reused per phase
    const int blk = blockIdx.x;
    const int tid = threadIdx.x;

    // ---- phase 1: front, ONE unit per block.
    // blocks 0..97: q head; 98..161: scatter band (disjoint mask reads);
    // 162..255: arrive only.
    if (blk < 98) {
        // q[b][d][t][n] = normalize_d(feats[b,n,:,t] @ Wh[:,d])
        int n = blk % NWIN, b = blk / NWIN;
        float4* f4    = (float4*)SMEM;               // 512 float4
        float4* psum4 = f4 + 512;                    // 256 float4
        float4* red4  = psum4 + 256;                 // 2 float4
        const float4* fp4 = (const float4*)(feats + (size_t)(b * NWIN + n) * 2048);
        for (int i = tid; i < 512; i += 256) f4[i] = fp4[i];
        __syncthreads();

        int d = tid & 127, ch = tid >> 7;
        float a0 = 0.f, a1 = 0.f, a2 = 0.f, a3 = 0.f;
        const float* wp = Wh + d;
        int c0 = ch * 256;
        #pragma unroll 8
        for (int c = c0; c < c0 + 256; ++c) {
            float w = wp[c * 128];
            float4 fv = f4[c];
            a0 += fv.x * w; a1 += fv.y * w; a2 += fv.z * w; a3 += fv.w * w;
        }
        psum4[tid] = make_float4(a0, a1, a2, a3);
        __syncthreads();

        float4 A;
        if (tid < 128) {
            float4 p0 = psum4[tid], p1 = psum4[128 + tid];
            A = make_float4(p0.x + p1.x, p0.y + p1.y, p0.z + p1.z, p0.w + p1.w);
            float sx = A.x * A.x, sy = A.y * A.y, sz = A.z * A.z, sw = A.w * A.w;
            for (int off = 32; off; off >>= 1) {
                sx += __shfl_down(sx, off); sy += __shfl_down(sy, off);
                sz += __shfl_down(sz, off); sw += __shfl_down(sw, off);
            }
            if ((tid & 63) == 0) red4[tid >> 6] = make_float4(sx, sy, sz, sw);
        }
        __syncthreads();
        if (tid < 128) {
            float4 r0 = red4[0], r1 = red4[1];
            float ix = 1.f / fmaxf(sqrtf(r0.x + r1.x), 1e-12f);
            float iy = 1.f / fmaxf(sqrtf(r0.y + r1.y), 1e-12f);
            float iz = 1.f / fmaxf(sqrtf(r0.z + r1.z), 1e-12f);
            float iw = 1.f / fmaxf(sqrtf(r0.w + r1.w), 1e-12f);
            float* qb = q + (size_t)(b * 128 + d) * 4 * QLD + n;
            qb[0 * QLD] = A.x * ix;
            qb[1 * QLD] = A.y * iy;
            qb[2 * QLD] = A.z * iz;
            qb[3 * QLD] = A.w * iw;
        }
    } else if (blk < 162) {
        // scatter band (R0/R1-proven): block = (bt, rb). Rows [32rb, 32rb+31],
        // disjoint coalesced mask reads; each pixel hits <=4 windows; LDS
        // histogram then global atomicAdd into zero-initialized ws.
        int u  = blk - 98;
        int rb = u & 7;
        int bt = u >> 3;
        float* loc = SMEM;                           // [2 wy-slots][7 wx][64 s]
        for (int i = tid; i < 2 * 7 * 64; i += 256) loc[i] = 0.f;
        __syncthreads();

        int x  = tid;                                // column
        int cx = x >> 5;
        int wx0 = cx - 1, wx1 = cx;
        bool wx0v = (wx0 >= 0), wx1v = (wx1 <= 6);
        float cw = ((x < 32) || (x >= 224)) ? 1.f : 0.5f;
        bool s0v = (rb >= 1);                        // wy = rb-1
        bool s1v = (rb <= 6);                        // wy = rb
        const int* mrow = mask + bt * 65536 + (rb * 32) * 256;

        #pragma unroll 4
        for (int k = 0; k < 32; ++k) {
            int y = rb * 32 + k;
            int s = mrow[k * 256 + x];
            float rw = ((y < 32) || (y >= 224)) ? 1.f : 0.5f;
            float w = rw * cw;
            if (s0v) {
                if (wx0v) atomicAdd(&loc[0 * 448 + wx0 * 64 + s], w);
                if (wx1v) atomicAdd(&loc[0 * 448 + wx1 * 64 + s], w);
            }
            if (s1v) {
                if (wx0v) atomicAdd(&loc[1 * 448 + wx0 * 64 + s], w);
                if (wx1v) atomicAdd(&loc[1 * 448 + wx1 * 64 + s], w);
            }
        }
        __syncthreads();
        for (int i = tid; i < 2 * 7 * 64; i += 256) {
            int slot = i / 448;
            int wx   = (i / 64) % 7;
            int s    = i & 63;
            bool valid = slot == 0 ? s0v : s1v;
            float v = loc[i];
            if (valid && v != 0.f) {
                int wy = rb - 1 + slot;
                atomicAdd(&ws[(bt * 64 + s) * QLD + wy * 7 + wx], v);
            }
        }
    }
    // ---- barrier 0: 256 arrive, all wait (all run phase 2)
    __syncthreads();
    if (tid == 0) {
        fence_rel();
        arrive8(bars + B0);
        poll8(bars + B0);
        fence_acq();
    }
    __syncthreads();

    // ---- phase 2: qsp[b][t][d][s], one output per thread (65536 threads)
    {
        int t2 = blk * 256 + tid;
        int s = t2 & 63;
        int d = (t2 >> 6) & 127;
        int t = (t2 >> 13) & 3;
        int b = t2 >> 15;
        const float4* qrow = (const float4*)(q + (size_t)((b * 128 + d) * 4 + t) * QLD);
        const float4* wrow = (const float4*)(ws + (size_t)((b * 4 + t) * 64 + s) * QLD);
        float acc = 0.f, den = 0.f;
        #pragma unroll
        for (int i = 0; i < 13; ++i) {
            float4 w = wrow[i];
            float4 qv = qrow[i];
            den += w.x + w.y + w.z + w.w;
            acc += qv.x * w.x + qv.y * w.y + qv.z * w.z + qv.w * w.w;
        }
        qsp[t2] = acc / (den + 1e-20f);
    }
    // ---- barrier 1: 256 arrive; only blocks 0..5 wait
    __syncthreads();
    if (tid == 0) { fence_rel(); arrive8(bars + B1); }
    if (blk >= 6) return;
    if (tid == 0) { poll8(bars + B1); fence_acq(); }
    __syncthreads();

    // ---- phase 3: As + zero_softmax (blocks 0..5)
    {
        int t = blk % 3, b = blk / 3;
        if (blk == 0 && tid == 0) out[0] = 0.f;      // loss accumulator
        float4* qaT4 = (float4*)SMEM;                // [s][d-swizzled] 32 KB
        float4* qbT4 = qaT4 + 2048;                  // 32 KB

        {
            const float4* gA = (const float4*)(qsp + (size_t)(b * 4 + t) * 8192);
            const float4* gB = (const float4*)(qsp + (size_t)(b * 4 + t + 1) * 8192);
            float* qaF = (float*)qaT4;
            float* qbF = (float*)qbT4;
            #pragma unroll
            for (int it = 0; it < 8; ++it) {
                int idx = it * 256 + tid;            // float4 index over [d][s/4]
                int d = idx >> 4, s0 = (idx & 15) << 2;
                float4 va = gA[idx];
                float4 vb = gB[idx];
                int g = d >> 2, c = d & 3;
                #pragma unroll
                for (int u = 0; u < 4; ++u) {
                    int s = s0 + u;
                    int w = (s * 32 + (g ^ (s & 31))) * 4 + c;
                    float fa = (u == 0) ? va.x : (u == 1) ? va.y : (u == 2) ? va.z : va.w;
                    float fb = (u == 0) ? vb.x : (u == 1) ? vb.y : (u == 2) ? vb.z : vb.w;
                    qaF[w] = fa;
                    qbF[w] = fb;
                }
            }
        }
        __syncthreads();

        const int nl = tid >> 4, ml = tid & 15;
        float acc[16];
        #pragma unroll
        for (int i = 0; i < 16; ++i) acc[i] = 0.f;
        #pragma unroll 8
        for (int k4 = 0; k4 < 32; ++k4) {
            float4 av[4], bv[4];
            #pragma unroll
            for (int i = 0; i < 4; ++i) { int n = nl + 16 * i; av[i] = qaT4[n * 32 + (k4 ^ (n & 31))]; }
            #pragma unroll
            for (int j = 0; j < 4; ++j) { int m = ml + 16 * j; bv[j] = qbT4[m * 32 + (k4 ^ (m & 31))]; }
            #pragma unroll
            for (int i = 0; i < 4; ++i)
                #pragma unroll
                for (int j = 0; j < 4; ++j)
                    acc[i * 4 + j] += av[i].x * bv[j].x + av[i].y * bv[j].y
                                    + av[i].z * bv[j].z + av[i].w * bv[j].w;
        }
        __syncthreads();

        float* eb = (float*)qaT4;          // [64][65]
        float* rs = (float*)qbT4;          // [64]
        float* cs = rs + 64;               // [64]
        #pragma unroll
        for (int i = 0; i < 4; ++i)
            #pragma unroll
            for (int j = 0; j < 4; ++j) {
                int n = nl + 16 * i, m = ml + 16 * j;
                float x = acc[i * 4 + j] * (1.f / 0.07f);
                float e = expf(x) - 1.f;
                eb[n * 65 + m] = e * e;
            }
        __syncthreads();
        if (tid < 128) {
            int r = tid & 63; bool isrow = tid < 64;
            float a = 0.f;
            #pragma unroll
            for (int k = 0; k < 64; ++k) a += isrow ? eb[r * 65 + k] : eb[k * 65 + r];
            (isrow ? rs : cs)[r] = a + 1e-5f;
        }
        __syncthreads();
        float* p12  = a12  + (b * 3 + t) * 4096;
        float* p12T = a12T + (b * 3 + t) * 4096;
        float* p21  = a21  + (b * 3 + t) * 4096;
        float* p21T = a21T + (b * 3 + t) * 4096;
        #pragma unroll
        for (int i = 0; i < 4; ++i)
            #pragma unroll
            for (int j = 0; j < 4; ++j) {
                int n = nl + 16 * i, m = ml + 16 * j;
                float v   = eb[n * 65 + m];
                float v12 = v / rs[n];           // A12[n][m]
                float v21 = v / cs[m];           // A21[m][n]
                p12 [n * 64 + m] = v12;
                p12T[m * 64 + n] = v12;
                p21 [m * 64 + n] = v21;
                p21T[n * 64 + m] = v21;          // A21^T[n][m]
            }
    }
    // ---- barrier 2: 6 arrive; blocks 0..3 wait
    __syncthreads();
    if (tid == 0) {
        fence_rel();
        __hip_atomic_fetch_add(&bars[C2], 1, __ATOMIC_RELAXED, __HIP_MEMORY_SCOPE_AGENT);
    }
    if (blk >= 4) return;
    if (tid == 0) {
        while (__hip_atomic_load(&bars[C2], __ATOMIC_RELAXED,
                                 __HIP_MEMORY_SCOPE_AGENT) < 6)
            __builtin_amdgcn_s_sleep(1);
        fence_acq();
    }
    __syncthreads();

    // ---- phase 4: chain matmuls + fused loss (blocks 0..3)
    {
        int path = blk & 1, b = blk >> 1;
        float* M0 = SMEM;
        float* M1 = SMEM + 4096;
        float* M2 = SMEM + 8192;
        float* M3 = SMEM + 12288;

        const float4* L0 = (const float4*)(a12  + (b * 3 + 0) * 4096);  // A12_0 rows
        const float4* L1 = (const float4*)(a12T + (b * 3 + 1) * 4096);  // A12_1^T rows
        const float4* L2 = (const float4*)(a21T + (b * 3 + 0) * 4096);  // A21_0^T rows
        const float4* L3 = (const float4*)(a21  + (b * 3 + 1) * 4096);  // A21_1 rows
        const float4* L4 = (const float4*)(a12T + (b * 3 + 2) * 4096);  // A12_2^T rows
        const float4* L5 = (const float4*)(a21  + (b * 3 + 2) * 4096);  // A21_2 rows

        float4 pf[6][4];
        #pragma unroll
        for (int it = 0; it < 4; ++it) {
            int idx = it * 256 + tid;
            pf[0][it] = L0[idx];
            pf[1][it] = L1[idx];
            pf[2][it] = L2[idx];
            pf[3][it] = L3[idx];
        }
        if (path) {
            #pragma unroll
            for (int it = 0; it < 4; ++it) {
                int idx = it * 256 + tid;
                pf[4][it] = L4[idx];
                pf[5][it] = L5[idx];
            }
        }
        __syncthreads();                 // phase-3 LDS reads fully retired
        dump_mat(M0, pf[0]);
        dump_mat(M1, pf[1]);
        dump_mat(M2, pf[2]);
        dump_mat(M3, pf[3]);
        __syncthreads();

        int half = tid >> 7;
        float hacc[32];
        #pragma unroll
        for (int i = 0; i < 32; ++i) hacc[i] = 0.f;
        mmh_sw(hacc, half ? M2 : M0, half ? M3 : M1);   // P | R1T
        __syncthreads();
        wrh_sw(half ? M3 : M1, hacc);                    // P -> M1, R1T -> M3
        if (path) { dump_mat(M0, pf[4]); dump_mat(M2, pf[5]); }
        __syncthreads();

        if (path == 0) {
            float acc[16];
            mm256_sw(acc, M1, M3);                       // aa1 = P @ R1
            store_loss(acc, out + 1 + b * 4096, out, M0);
        } else {
            float hacc2[32];
            #pragma unroll
            for (int i = 0; i < 32; ++i) hacc2[i] = 0.f;
            mmh_sw(hacc2, half ? M3 : M1, half ? M2 : M0);  // L | RT
            __syncthreads();
            wrh_sw(half ? M1 : M0, hacc2);                  // L -> M0, RT -> M1
            __syncthreads();
            float acc[16];
            mm256_sw(acc, M0, M1);                          // aa2 = L @ R
            store_loss(acc, out + 1 + (2 + b) * 4096, out, M2);
        }
    }
}

// ---------------------------------------------------------------------------
extern "C" void kernel_launch(void* const* d_in, const int* in_sizes, int n_in,
                              void* d_out, int out_size, void* d_ws, size_t ws_size,
                              hipStream_t stream) {
    const float* feats = (const float*)d_in[0];
    const float* Wh    = (const float*)d_in[1];
    const int*   mask  = (const int*)d_in[2];
    float* out = (float*)d_out;
    float* ws  = (float*)d_ws;

    float* ws_sums = ws + OFF_WS;
    float* q       = ws + OFF_Q;
    float* qsp     = ws + OFF_QSP;
    float* a12     = ws + OFF_A12;
    float* a12T    = ws + OFF_A12T;
    float* a21     = ws + OFF_A21;
    float* a21T    = ws + OFF_A21T;
    int*   bars    = (int*)(ws + OFF_BARF);

    // one memset zeroes ws (atomic accumulation target) + barrier counters
    hipMemsetAsync(d_ws, 0, (OFF_BARF + 640) * sizeof(float), stream);
    k_all<<<256, 256, 0, stream>>>(mask, feats, Wh, ws_sums, q, qsp,
                                   a12, a12T, a21, a21T, out, bars);
}

// Round 11
// 145.303 us; speedup vs baseline: 1.0502x; 1.0502x over previous
//
#include <hip/hip_runtime.h>
#include <hip/hip_bf16.h>

// Problem constants (fixed by reference setup_inputs)
constexpr int NWIN = 49;     // 7x7 windows
constexpr int QLD  = 52;     // padded row length for 49-length rows (13 float4)

// workspace layout (float offsets)
constexpr int OFF_WS   = 0;            // [8][64][52]      = 26624 (bt, s, win)
constexpr int OFF_BAR  = 26624;        // 16 ints (barrier counter; zeroed by k_front)
constexpr int OFF_Q    = 26640;        // [2][128][4][52]  = 53248 (b, d, t, n)
constexpr int OFF_A12  = 79888;        // [2][3][64][64]
constexpr int OFF_A12T = 104464;
constexpr int OFF_A21  = 129040;
constexpr int OFF_A21T = 153616;       // end = 178192 floats (~713 KB)

// ---------------------------------------------------------------------------
__device__ __forceinline__ void fence_rel() {
    __builtin_amdgcn_fence(__ATOMIC_RELEASE, "agent");   // L2 writeback
}
__device__ __forceinline__ void fence_acq() {
    __builtin_amdgcn_fence(__ATOMIC_ACQUIRE, "agent");   // L2/L1 invalidate
}

// ---------------------------------------------------------------------------
// K1: fused front end — blocks [0,392): scatter; blocks [392,490): q head.
// (R6-proven fastest front; direct ws stores, no atomics, no memset needed.)
__global__ void __launch_bounds__(256, 1)
k_front(const int* __restrict__ mask, const float* __restrict__ feats,
        const float* __restrict__ Wh, float* __restrict__ ws, float* __restrict__ q,
        int* __restrict__ bars) {
    if (blockIdx.x == 0 && threadIdx.x == 0) bars[0] = 0;   // micro-barrier init
    if (blockIdx.x < 392) {
        // ws[bt][s][win] = sum over window pixels with label s of 1/sm.
        // sum_win ws[bt][s][:] == pixel count of label s, so the qsp
        // denominator is just the row sum. Pad cols 49..51 zeroed.
        int win = blockIdx.x % NWIN;
        int bt  = blockIdx.x / NWIN;
        int wy = win / 7, wx = win % 7;
        __shared__ float loc[64];
        if (threadIdx.x < 64) loc[threadIdx.x] = 0.f;
        __syncthreads();
        const int* base = mask + bt * 65536 + (wy * 32) * 256 + wx * 32;
        #pragma unroll
        for (int it = 0; it < 16; ++it) {
            int idx = it * 256 + (int)threadIdx.x;
            int r = idx >> 6, c = idx & 63;
            int s = base[r * 256 + c];
            int y = wy * 32 + r, x = wx * 32 + c;
            float w = 1.f;
            if (y >= 32 && y < 224) w *= 0.5f;   // row coverage = 2
            if (x >= 32 && x < 224) w *= 0.5f;   // col coverage = 2
            atomicAdd(&loc[s], w);
        }
        __syncthreads();
        if (threadIdx.x < 64) {
            ws[(bt * 64 + (int)threadIdx.x) * QLD + win] = loc[threadIdx.x];
        } else if (win == 0) {
            int s = threadIdx.x & 63;
            int col = 49 + (int)(threadIdx.x >> 6) - 1;   // 49,50,51
            ws[(bt * 64 + s) * QLD + col] = 0.f;
        }
    } else {
        // q[b][d][t][n] = normalize_d(feats[b,n,:,t] @ Wh[:,d])
        int bid = blockIdx.x - 392;
        int n = bid % NWIN, b = bid / NWIN;
        __shared__ float4 f4[512];        // feats[c][t] as float4 over t
        __shared__ float4 psum4[256];
        __shared__ float4 red4[2];
        const float4* fp4 = (const float4*)(feats + (size_t)(b * NWIN + n) * 2048);
        for (int i = threadIdx.x; i < 512; i += 256) f4[i] = fp4[i];
        __syncthreads();

        int d = threadIdx.x & 127, ch = threadIdx.x >> 7;
        float a0 = 0.f, a1 = 0.f, a2 = 0.f, a3 = 0.f;
        const float* wp = Wh + d;
        int c0 = ch * 256;
        #pragma unroll 8
        for (int c = c0; c < c0 + 256; ++c) {
            float w = wp[c * 128];
            float4 fv = f4[c];
            a0 += fv.x * w; a1 += fv.y * w; a2 += fv.z * w; a3 += fv.w * w;
        }
        psum4[threadIdx.x] = make_float4(a0, a1, a2, a3);
        __syncthreads();

        float4 A;
        if (threadIdx.x < 128) {
            float4 p0 = psum4[threadIdx.x], p1 = psum4[128 + threadIdx.x];
            A = make_float4(p0.x + p1.x, p0.y + p1.y, p0.z + p1.z, p0.w + p1.w);
            float sx = A.x * A.x, sy = A.y * A.y, sz = A.z * A.z, sw = A.w * A.w;
            for (int off = 32; off; off >>= 1) {
                sx += __shfl_down(sx, off); sy += __shfl_down(sy, off);
                sz += __shfl_down(sz, off); sw += __shfl_down(sw, off);
            }
            if ((threadIdx.x & 63) == 0) red4[threadIdx.x >> 6] = make_float4(sx, sy, sz, sw);
        }
        __syncthreads();
        if (threadIdx.x < 128) {
            float4 r0 = red4[0], r1 = red4[1];
            float ix = 1.f / fmaxf(sqrtf(r0.x + r1.x), 1e-12f);
            float iy = 1.f / fmaxf(sqrtf(r0.y + r1.y), 1e-12f);
            float iz = 1.f / fmaxf(sqrtf(r0.z + r1.z), 1e-12f);
            float iw = 1.f / fmaxf(sqrtf(r0.w + r1.w), 1e-12f);
            float* qb = q + (size_t)(b * 128 + d) * 4 * QLD + n;
            qb[0 * QLD] = A.x * ix;
            qb[1 * QLD] = A.y * iy;
            qb[2 * QLD] = A.z * iz;
            qb[3 * QLD] = A.w * iw;
        }
    }
}

// ---------------------------------------------------------------------------
// Chain helpers (proven): XOR-4-swizzled LDS, register prefetch.
// Layout: element (r,k) at M[r*64 + (((k>>2)^(r&15))<<2)+(k&3)].
__device__ __forceinline__ void dump_mat(float* M, const float4* v) {
    #pragma unroll
    for (int it = 0; it < 4; ++it) {
        int idx = it * 256 + (int)threadIdx.x;
        int r = idx >> 4, c4 = (idx & 15) << 2;
        *(float4*)&M[r * 64 + (c4 ^ ((r & 15) << 2))] = v[it];
    }
}

__device__ __forceinline__ void mmh_sw(float* acc, const float* Ra, const float* Rb) {
    int lt = threadIdx.x & 127;
    int nl = lt >> 3, ml = lt & 7;
    int sxa = nl << 2;
    #pragma unroll
    for (int k0 = 0; k0 < 64; k0 += 4) {
        float4 av[4], bv[8];
        #pragma unroll
        for (int i = 0; i < 4; ++i)
            av[i] = *(const float4*)&Ra[(nl + 16 * i) * 64 + (k0 ^ sxa)];
        #pragma unroll
        for (int j = 0; j < 8; ++j) {
            int m = ml + 8 * j;
            bv[j] = *(const float4*)&Rb[m * 64 + (k0 ^ ((m & 15) << 2))];
        }
        #pragma unroll
        for (int i = 0; i < 4; ++i)
            #pragma unroll
            for (int j = 0; j < 8; ++j)
                acc[i * 8 + j] += av[i].x * bv[j].x + av[i].y * bv[j].y
                                + av[i].z * bv[j].z + av[i].w * bv[j].w;
    }
}

__device__ __forceinline__ void wrh_sw(float* M, const float* acc) {
    int lt = threadIdx.x & 127;
    int nl = lt >> 3, ml = lt & 7;
    #pragma unroll
    for (int i = 0; i < 4; ++i)
        #pragma unroll
        for (int j = 0; j < 8; ++j) {
            int r = nl + 16 * i, k = ml + 8 * j;
            M[r * 64 + (((k & ~3) ^ ((r & 15) << 2)) | (k & 3))] = acc[i * 8 + j];
        }
}

__device__ __forceinline__ void mm256_sw(float* acc, const float* Ra, const float* Rb) {
    int tid = threadIdx.x;
    int nl = tid >> 4, ml = tid & 15;
    int sxa = nl << 2, sxb = ml << 2;
    #pragma unroll
    for (int i = 0; i < 16; ++i) acc[i] = 0.f;
    #pragma unroll 4
    for (int k0 = 0; k0 < 64; k0 += 4) {
        float4 av[4], bv[4];
        #pragma unroll
        for (int i = 0; i < 4; ++i)
            av[i] = *(const float4*)&Ra[(nl + 16 * i) * 64 + (k0 ^ sxa)];
        #pragma unroll
        for (int j = 0; j < 4; ++j)
            bv[j] = *(const float4*)&Rb[(ml + 16 * j) * 64 + (k0 ^ sxb)];
        #pragma unroll
        for (int i = 0; i < 4; ++i)
            #pragma unroll
            for (int j = 0; j < 4; ++j)
                acc[i * 4 + j] += av[i].x * bv[j].x + av[i].y * bv[j].y
                                + av[i].z * bv[j].z + av[i].w * bv[j].w;
    }
}

__device__ __forceinline__ void store_loss(const float* acc, float* __restrict__ aa,
                                           float* __restrict__ out, float* red) {
    int tid = threadIdx.x;
    int nl = tid >> 4, ml = tid & 15;
    #pragma unroll
    for (int i = 0; i < 4; ++i)
        #pragma unroll
        for (int j = 0; j < 4; ++j)
            aa[(nl + 16 * i) * 64 + (ml + 16 * j)] = acc[i * 4 + j];
    int l = tid & 63;
    float part = 0.f;
    #pragma unroll
    for (int i = 0; i < 4; ++i) {
        float rsum = acc[i * 4 + 0] + acc[i * 4 + 1] + acc[i * 4 + 2] + acc[i * 4 + 3];
        rsum += __shfl_down(rsum, 8, 16);
        rsum += __shfl_down(rsum, 4, 16);
        rsum += __shfl_down(rsum, 2, 16);
        rsum += __shfl_down(rsum, 1, 16);
        float dv = __shfl(acc[5 * i], (l & 48) | nl, 64);
        if ((l & 15) == 0) part += logf(rsum + 6.4e-19f) - logf(dv + 1e-20f);
    }
    for (int off = 32; off; off >>= 1) part += __shfl_down(part, off);
    if (l == 0) red[tid >> 6] = part;
    __syncthreads();
    if (tid == 0) atomicAdd(out, (red[0] + red[1] + red[2] + red[3]) * (1.f / 128.f));
}

// ---------------------------------------------------------------------------
// K2: local-qsp + As + zero_softmax + micro-barrier + chain. grid = 6 blocks.
// Each block (b,t) computes the qsp slices it needs itself: q chunks staged
// coalesced into LDS (fixes R4's global-broadcast latency), ws rows in regs.
__global__ void __launch_bounds__(256, 1)
k_aschain(const float* __restrict__ q, const float* __restrict__ wsg,
          float* __restrict__ a12s, float* __restrict__ a12Ts,
          float* __restrict__ a21s, float* __restrict__ a21Ts,
          float* __restrict__ out, int* __restrict__ bars) {
    __shared__ __align__(16) float SMEM[16384];     // 64 KB, reused per phase
    const int blk = blockIdx.x;
    const int tid = threadIdx.x;
    const int t = blk % 3, b = blk / 3;
    const int s = tid & 63, wv = tid >> 6;

    if (blk == 0 && tid == 0) out[0] = 0.f;          // loss accumulator

    // ---- ws rows for slices t, t+1 in registers (pads are zero)
    float4 wsA[13], wsB[13];
    float denA = 0.f, denB = 0.f;
    {
        const float4* wra = (const float4*)(wsg + (size_t)((b * 4 + t) * 64 + s) * QLD);
        const float4* wrb = (const float4*)(wsg + (size_t)((b * 4 + t + 1) * 64 + s) * QLD);
        #pragma unroll
        for (int i = 0; i < 13; ++i) {
            wsA[i] = wra[i]; wsB[i] = wrb[i];
            denA += wsA[i].x + wsA[i].y + wsA[i].z + wsA[i].w;
            denB += wsB[i].x + wsB[i].y + wsB[i].z + wsB[i].w;
        }
    }
    const float invA = 1.f / (denA + 1e-20f);
    const float invB = 1.f / (denB + 1e-20f);

    // LDS regions for the chunked qsp+mm (29.7 KB of the 64 KB)
    float4* qstA = (float4*)SMEM;          // [32 d-rows][13]  staged q slice A
    float4* qstB = qstA + 416;             // staged q slice B
    float4* qaC  = qstB + 416;             // [64 s][8 g, XOR3-swizzled] qspA chunk
    float4* qbC  = qaC + 512;              // qspB chunk

    const float4* q4 = (const float4*)q;
    const int nl = tid >> 4, ml = tid & 15;
    float acc[16];
    #pragma unroll
    for (int i = 0; i < 16; ++i) acc[i] = 0.f;

    for (int c4 = 0; c4 < 4; ++c4) {
        const int D = c4 * 32;
        __syncthreads();
        // stage q chunk rows (coalesced: 13 consecutive float4 per row)
        for (int idx = tid; idx < 832; idx += 256) {
            int which = idx >= 416;
            int loc = which ? idx - 416 : idx;
            int r = loc / 13, i = loc - r * 13;
            float4 v = q4[((size_t)(b * 128 + D + r) * 4 + t + which) * 13 + i];
            (which ? qstB : qstA)[r * 13 + i] = v;
        }
        __syncthreads();
        // qsp for this chunk: thread (wv, s) covers d-local 8wv..8wv+7
        float oa[8], ob[8];
        #pragma unroll
        for (int u = 0; u < 8; ++u) {
            int dl = 8 * wv + u;
            const float4* qa = qstA + dl * 13;
            const float4* qb = qstB + dl * 13;
            float sa = 0.f, sb = 0.f;
            #pragma unroll
            for (int i = 0; i < 13; ++i) {
                float4 va = qa[i];
                sa += va.x * wsA[i].x + va.y * wsA[i].y + va.z * wsA[i].z + va.w * wsA[i].w;
            }
            #pragma unroll
            for (int i = 0; i < 13; ++i) {
                float4 vb = qb[i];
                sb += vb.x * wsB[i].x + vb.y * wsB[i].y + vb.z * wsB[i].z + vb.w * wsB[i].w;
            }
            oa[u] = sa * invA; ob[u] = sb * invB;
        }
        #pragma unroll
        for (int h = 0; h < 2; ++h) {
            int gl = 2 * wv + h;
            int w = s * 8 + (gl ^ (s & 7));
            qaC[w] = make_float4(oa[4 * h], oa[4 * h + 1], oa[4 * h + 2], oa[4 * h + 3]);
            qbC[w] = make_float4(ob[4 * h], ob[4 * h + 1], ob[4 * h + 2], ob[4 * h + 3]);
        }
        __syncthreads();
        // partial mm over this chunk's 32 k-values
        #pragma unroll
        for (int k4 = 0; k4 < 8; ++k4) {
            float4 av[4], bv[4];
            #pragma unroll
            for (int i = 0; i < 4; ++i) { int n = nl + 16 * i; av[i] = qaC[n * 8 + (k4 ^ (n & 7))]; }
            #pragma unroll
            for (int j = 0; j < 4; ++j) { int m = ml + 16 * j; bv[j] = qbC[m * 8 + (k4 ^ (m & 7))]; }
            #pragma unroll
            for (int i = 0; i < 4; ++i)
                #pragma unroll
                for (int j = 0; j < 4; ++j)
                    acc[i * 4 + j] += av[i].x * bv[j].x + av[i].y * bv[j].y
                                    + av[i].z * bv[j].z + av[i].w * bv[j].w;
        }
    }
    __syncthreads();

    // ---- zero_softmax both ways; emit a12/a12T/a21/a21T (proven)
    {
        float* eb = SMEM;            // [64][65]
        float* rs = SMEM + 4160;     // [64]
        float* cs = SMEM + 4224;     // [64]
        #pragma unroll
        for (int i = 0; i < 4; ++i)
            #pragma unroll
            for (int j = 0; j < 4; ++j) {
                int n = nl + 16 * i, m = ml + 16 * j;
                float x = acc[i * 4 + j] * (1.f / 0.07f);
                float e = expf(x) - 1.f;
                eb[n * 65 + m] = e * e;
            }
        __syncthreads();
        if (tid < 128) {
            int r = tid & 63; bool isrow = tid < 64;
            float a = 0.f;
            #pragma unroll
            for (int k = 0; k < 64; ++k) a += isrow ? eb[r * 65 + k] : eb[k * 65 + r];
            (isrow ? rs : cs)[r] = a + 1e-5f;
        }
        __syncthreads();
        float* p12  = a12s  + (b * 3 + t) * 4096;
        float* p12T = a12Ts + (b * 3 + t) * 4096;
        float* p21  = a21s  + (b * 3 + t) * 4096;
        float* p21T = a21Ts + (b * 3 + t) * 4096;
        #pragma unroll
        for (int i = 0; i < 4; ++i)
            #pragma unroll
            for (int j = 0; j < 4; ++j) {
                int n = nl + 16 * i, m = ml + 16 * j;
                float v   = eb[n * 65 + m];
                float v12 = v / rs[n];           // A12[n][m]
                float v21 = v / cs[m];           // A21[m][n]
                p12 [n * 64 + m] = v12;
                p12T[m * 64 + n] = v12;
                p21 [m * 64 + n] = v21;
                p21T[n * 64 + m] = v21;          // A21^T[n][m]
            }
    }

    // ---- micro-barrier: 6 arrive, blocks 0..3 wait (cheap: 6 RMWs, 4 pollers)
    __syncthreads();
    if (tid == 0) {
        fence_rel();
        __hip_atomic_fetch_add(&bars[0], 1, __ATOMIC_RELAXED, __HIP_MEMORY_SCOPE_AGENT);
    }
    if (blk >= 4) return;
    if (tid == 0) {
        while (__hip_atomic_load(&bars[0], __ATOMIC_RELAXED,
                                 __HIP_MEMORY_SCOPE_AGENT) < 6)
            __builtin_amdgcn_s_sleep(1);
        fence_acq();
    }
    __syncthreads();

    // ---- chain matmuls + fused loss (blocks 0..3; proven)
    {
        int path = blk & 1, bc = blk >> 1;
        float* M0 = SMEM;
        float* M1 = SMEM + 4096;
        float* M2 = SMEM + 8192;
        float* M3 = SMEM + 12288;

        const float4* L0 = (const float4*)(a12s  + (bc * 3 + 0) * 4096);  // A12_0 rows
        const float4* L1 = (const float4*)(a12Ts + (bc * 3 + 1) * 4096);  // A12_1^T rows
        const float4* L2 = (const float4*)(a21Ts + (bc * 3 + 0) * 4096);  // A21_0^T rows
        const float4* L3 = (const float4*)(a21s  + (bc * 3 + 1) * 4096);  // A21_1 rows
        const float4* L4 = (const float4*)(a12Ts + (bc * 3 + 2) * 4096);  // A12_2^T rows
        const float4* L5 = (const float4*)(a21s  + (bc * 3 + 2) * 4096);  // A21_2 rows

        float4 pf[6][4];
        #pragma unroll
        for (int it = 0; it < 4; ++it) {
            int idx = it * 256 + tid;
            pf[0][it] = L0[idx];
            pf[1][it] = L1[idx];
            pf[2][it] = L2[idx];
            pf[3][it] = L3[idx];
        }
        if (path) {
            #pragma unroll
            for (int it = 0; it < 4; ++it) {
                int idx = it * 256 + tid;
                pf[4][it] = L4[idx];
                pf[5][it] = L5[idx];
            }
        }
        __syncthreads();
        dump_mat(M0, pf[0]);
        dump_mat(M1, pf[1]);
        dump_mat(M2, pf[2]);
        dump_mat(M3, pf[3]);
        __syncthreads();

        int half = tid >> 7;
        float hacc[32];
        #pragma unroll
        for (int i = 0; i < 32; ++i) hacc[i] = 0.f;
        mmh_sw(hacc, half ? M2 : M0, half ? M3 : M1);   // P | R1T
        __syncthreads();
        wrh_sw(half ? M3 : M1, hacc);                    // P -> M1, R1T -> M3
        if (path) { dump_mat(M0, pf[4]); dump_mat(M2, pf[5]); }
        __syncthreads();

        if (path == 0) {
            float acc2[16];
            mm256_sw(acc2, M1, M3);                      // aa1 = P @ R1
            store_loss(acc2, out + 1 + bc * 4096, out, M0);
        } else {
            float hacc2[32];
            #pragma unroll
            for (int i = 0; i < 32; ++i) hacc2[i] = 0.f;
            mmh_sw(hacc2, half ? M3 : M1, half ? M2 : M0);  // L | RT
            __syncthreads();
            wrh_sw(half ? M1 : M0, hacc2);                  // L -> M0, RT -> M1
            __syncthreads();
            float acc2[16];
            mm256_sw(acc2, M0, M1);                         // aa2 = L @ R
            store_loss(acc2, out + 1 + (2 + bc) * 4096, out, M2);
        }
    }
}

// ---------------------------------------------------------------------------
extern "C" void kernel_launch(void* const* d_in, const int* in_sizes, int n_in,
                              void* d_out, int out_size, void* d_ws, size_t ws_size,
                              hipStream_t stream) {
    const float* feats = (const float*)d_in[0];
    const float* Wh    = (const float*)d_in[1];
    const int*   mask  = (const int*)d_in[2];
    float* out = (float*)d_out;
    float* ws  = (float*)d_ws;

    float* ws_sums = ws + OFF_WS;
    float* q       = ws + OFF_Q;
    float* a12     = ws + OFF_A12;
    float* a12T    = ws + OFF_A12T;
    float* a21     = ws + OFF_A21;
    float* a21T    = ws + OFF_A21T;
    int*   bars    = (int*)(ws + OFF_BAR);

    k_front<<<392 + 2 * NWIN, 256, 0, stream>>>(mask, feats, Wh, ws_sums, q, bars);
    k_aschain<<<6, 256, 0, stream>>>(q, ws_sums, a12, a12T, a21, a21T, out, bars);
}